// Round 8
// baseline (229.475 us; speedup 1.0000x reference)
//
#include <hip/hip_runtime.h>

#define N 256
#define C 128
#define H 4
#define D 32
#define NP (N*N)            // 65536 pairs
#define LN_EPS 1e-5f
#define LOG2E 1.4426950408889634f

// Block-wide barrier (LDS ordering only; global stores keep flying).
__device__ __forceinline__ void barrier_lgkm() {
    __asm__ volatile("s_waitcnt lgkmcnt(0)" ::: "memory");
    __builtin_amdgcn_sched_barrier(0);
    __builtin_amdgcn_s_barrier();
    __builtin_amdgcn_sched_barrier(0);
}
// Wave-local LDS drain (no barrier): orders this wave's ds ops only.
__device__ __forceinline__ void drain_lds() {
    __asm__ volatile("s_waitcnt lgkmcnt(0)" ::: "memory");
    __builtin_amdgcn_sched_barrier(0);
}

using f32x4 = __attribute__((ext_vector_type(4))) float;
using bf8   = __attribute__((ext_vector_type(8))) short;   // 8 x bf16 (4 VGPRs)
using u16x4 = __attribute__((ext_vector_type(4))) unsigned short;

__device__ __forceinline__ float bf2f(ushort u) {
    union { uint u; float f; } v; v.u = ((uint)u) << 16; return v.f;
}
__device__ __forceinline__ ushort f2bf(float f) {           // RNE
    union { float f; uint u; } v; v.f = f;
    uint u = v.u;
    u += 0x7fffu + ((u >> 16) & 1u);
    return (ushort)(u >> 16);
}
__device__ __forceinline__ ushort f2bf_trunc(float f) {     // truncate
    union { float f; uint u; } v; v.f = f;
    return (ushort)(v.u >> 16);
}

// ---------------------------------------------------------------- weights
__global__ __launch_bounds__(256) void prep_weights(
    const float* __restrict__ wq, const float* __restrict__ wk,
    const float* __restrict__ wv, const float* __restrict__ wg,
    const float* __restrict__ wb, const float* __restrict__ wo,
    ushort* __restrict__ Wcat, ushort* __restrict__ WbPad, ushort* __restrict__ Wo)
{
    int t = blockIdx.x * 256 + threadIdx.x;    // 65536 threads
    const float scale = 0.17677669529663689f * LOG2E;
    float v;
    if (t < 16384)       v = wq[t] * scale;
    else if (t < 32768)  v = wk[t - 16384];
    else if (t < 49152)  v = wv[t - 32768];
    else                 v = wg[t - 49152];
    Wcat[t] = f2bf(v);
    if (t < 16384) Wo[t] = f2bf(wo[t]);
    if (t < 2048)  WbPad[t] = (t < 512) ? f2bf(wb[t]) : (ushort)0;
}

// ---------------------------------------------------------------- fused LN + tri + QKVG
// ZERO block-wide barriers. 1024 blocks x 256 threads (4 waves); each wave
// is a fully independent pipeline over its own 16-row strip: LN -> own At
// strip -> A-frags (reads only own strip) -> tri MFMAs -> 4 projections with
// wave-private epilogue staging (At strip reused). Cross-wave deps: none.
// Waves drift apart and pipeline each other's memory latency naturally
// (the round-2..5 lockstep convoy is structurally impossible here).
// V goes DIRECTLY from acc registers to vbT[col][key] as packed 8B stores
// (4 waves' 32B pieces of each 128B line merge in the same-XCD L2).
__global__ __launch_bounds__(256, 4) void ln_proj(
    const float* __restrict__ x, const float* __restrict__ lnw,
    const float* __restrict__ lnb, const ushort* __restrict__ Wcat,
    const ushort* __restrict__ WbPad, const float* __restrict__ bg,
    ushort* __restrict__ qb, ushort* __restrict__ kb,
    ushort* __restrict__ vbT, ushort* __restrict__ gate,
    ushort* __restrict__ tri_p)
{
    __shared__ ushort At[64 * 128];    // 16 KB: 4 x wave-private 16-row strip
    int mt = blockIdx.x;               // 0..1023
    int t  = threadIdx.x;
    int wave = t >> 6, lane = t & 63;
    int lane32 = lane & 31, rsel = lane >> 5;
    int lrow = lane & 15, quad = lane >> 4;

    // ---- LN of the wave's OWN 16 rows (32 lanes/row, 2 rows/pass, 8 passes)
    {
        const float4 w4 = ((const float4*)lnw)[lane32];
        const float4 b4 = ((const float4*)lnb)[lane32];
        const float* xb = x + (size_t)mt * 64 * C;
        float4 xv[8];
        #pragma unroll
        for (int pp = 0; pp < 8; pp++) {
            int r = wave * 16 + pp * 2 + rsel;
            xv[pp] = ((const float4*)(xb + r * C))[lane32];
        }
        #pragma unroll
        for (int pp = 0; pp < 8; pp++) {
            int r = wave * 16 + pp * 2 + rsel;
            float4 v = xv[pp];
            float s  = v.x + v.y + v.z + v.w;
            float ss = v.x*v.x + v.y*v.y + v.z*v.z + v.w*v.w;
            #pragma unroll
            for (int m = 1; m < 32; m <<= 1) {
                s  += __shfl_xor(s, m, 64);
                ss += __shfl_xor(ss, m, 64);
            }
            float mean = s * (1.f / 128.f);
            float var  = ss * (1.f / 128.f) - mean * mean;
            float rstd = rsqrtf(var + LN_EPS);
            u16x4 o;
            o[0] = f2bf((v.x - mean) * rstd * w4.x + b4.x);
            o[1] = f2bf((v.y - mean) * rstd * w4.y + b4.y);
            o[2] = f2bf((v.z - mean) * rstd * w4.z + b4.z);
            o[3] = f2bf((v.w - mean) * rstd * w4.w + b4.w);
            int c8 = lane32 >> 1;
            int chunk = r * 16 + (c8 ^ (r & 7));
            *(u16x4*)&At[chunk * 8 + (lane32 & 1) * 4] = o;
        }
    }
    drain_lds();                       // wave-local: own writes visible

    // ---- A-frags from own strip only (no cross-wave reads)
    bf8 afr[4];
    #pragma unroll
    for (int ks = 0; ks < 4; ks++) {
        int row = wave * 16 + lrow;
        afr[ks] = *(const bf8*)&At[(row * 16 + ((ks * 4 + quad) ^ (row & 7))) * 8];
    }
    drain_lds();                       // frag reads done before strip reuse

    // ---- triangle bias for the wave's 16 pairs (4 MFMAs vs WbPad)
    {
        f32x4 at = (f32x4){0.f, 0.f, 0.f, 0.f};
        #pragma unroll
        for (int ks = 0; ks < 4; ks++) {
            bf8 bt = *(const bf8*)(WbPad + lrow * C + (ks * 4 + quad) * 8);
            at = __builtin_amdgcn_mfma_f32_16x16x32_bf16(afr[ks], bt, at, 0, 0, 0);
        }
        if (lrow < 4) {                // lrow = h
            int q = mt >> 2;
            int qc = q >> 4, quadq = (q >> 2) & 3, rr = q & 3;
            #pragma unroll
            for (int r = 0; r < 4; r++) {
                int k = (mt & 3) * 64 + wave * 16 + quad * 4 + r;
                int n = k >> 4, lk = k & 15;
                int lanet = quadq * 16 + lk;
                int v2 = n * 4 + rr, j = v2 >> 3, m2 = v2 & 7;
                tri_p[lrow * 65536 + ((qc * 8 + j) * 64 + lanet) * 8 + m2] =
                    f2bf(at[r] * LOG2E);
            }
        }
    }

    // ---- 4 projections; wave-private epilogue staging in own At strip
    ushort* Sw = At + wave * 16 * 128;     // 4 KB private [16 rows][128 cols]
    #pragma unroll 1
    for (int nt = 0; nt < 4; nt++) {
        const ushort* Wt = Wcat + (size_t)nt * 128 * C;
        f32x4 acc[8];
        #pragma unroll
        for (int ni = 0; ni < 8; ni++) acc[ni] = (f32x4){0.f, 0.f, 0.f, 0.f};

        #pragma unroll
        for (int ks = 0; ks < 4; ks++) {
            #pragma unroll
            for (int ni = 0; ni < 8; ni++) {
                bf8 b = *(const bf8*)(Wt + (size_t)(ni * 16 + lrow) * C + (ks * 4 + quad) * 8);
                acc[ni] = __builtin_amdgcn_mfma_f32_16x16x32_bf16(afr[ks], b, acc[ni], 0, 0, 0);
            }
        }

        if (nt == 2) {
            // direct register->global: 8B packed (4 keys) per col; block's
            // 4 waves fill each 128B line of vbT[col][key] in same-L2 pieces
            int i_row = mt >> 2;
            int keyoff = (mt & 3) * 64 + wave * 16 + quad * 4;
            #pragma unroll
            for (int ni = 0; ni < 8; ni++) {
                int col = ni * 16 + lrow;
                union { ushort us[4]; uint2 u2; } pk;
                #pragma unroll
                for (int r = 0; r < 4; r++) pk.us[r] = f2bf(acc[ni][r]);
                *(uint2*)&vbT[(size_t)(i_row * 128 + col) * N + keyoff] = pk.u2;
            }
        } else {
            ushort* dst = (nt == 0) ? qb : (nt == 1) ? kb : gate;
            #pragma unroll
            for (int ni = 0; ni < 8; ni++) {
                int col = ni * 16 + lrow;
                float gb = (nt == 3) ? bg[col] : 0.f;
                int colS = col ^ (quad << 3);      // swizzle col bits 3,4 by quad
                #pragma unroll
                for (int r = 0; r < 4; r++) {
                    float vv = acc[ni][r];
                    if (nt == 3) vv = 1.f / (1.f + __expf(-(vv + gb)));
                    Sw[(quad * 4 + r) * 128 + colS] = f2bf(vv);
                }
            }
            drain_lds();               // wave-local: staging visible, prior reads done
            #pragma unroll
            for (int it = 0; it < 4; it++) {
                int lin = it * 64 + lane;
                int row = lin >> 4, c8 = lin & 15;
                bf8 val = *(const bf8*)&Sw[row * 128 + (c8 ^ ((row >> 2) & 3)) * 8];
                *(bf8*)&dst[(size_t)(mt * 64 + wave * 16 + row) * C + c8 * 8] = val;
            }
        }
    }
}

// ---------------------------------------------------------------- fused attention + out-proj
// Grid (i=256, qh=2), 512 threads = 8 waves; wave owns q-chunk qc = qh*8+w.
// T14: next head's K/V/Q staged into registers right after the current
// head's LDS writes -- HBM latency hides under QK^T/softmax/PV compute.
__global__ __launch_bounds__(512, 4) void attn_out(
    const ushort* __restrict__ qb, const ushort* __restrict__ kb,
    const ushort* __restrict__ vbT, const ushort* __restrict__ tri_p,
    const float* __restrict__ mask, const ushort* __restrict__ gate,
    const ushort* __restrict__ Wo, const float* __restrict__ bo,
    float* __restrict__ out)
{
    __shared__ ushort Kf[8192];       // 16 KB, per-head K fragments
    __shared__ ushort Vf[8192];       // 16 KB, per-head V fragments (swizzled)
    __shared__ ushort Pf[8][2048];    // 32 KB: per-wave P / O-transpose buffer

    int i  = blockIdx.x;
    int qh = blockIdx.y;
    int t  = threadIdx.x;
    int wave = t >> 6, lane = t & 63;
    int lrow = lane & 15, quad = lane >> 4;
    int qc = qh * 8 + wave;            // q-chunk 0..15

    // mask bias per lane's 16 key-columns (log2e-folded), head-invariant
    float mb[16];
    #pragma unroll
    for (int n = 0; n < 16; n++)
        mb[n] = (1e9f * LOG2E) * (mask[i * N + n * 16 + lrow] - 1.0f);

    f32x4 oacc[8];
    #pragma unroll
    for (int ct = 0; ct < 8; ct++) oacc[ct] = (f32x4){0.f, 0.f, 0.f, 0.f};

    ushort* Pw = &Pf[wave][0];
    const int pq = quad * 32 + (lrow & 7);
    const int l3 = (lrow >> 3) & 1;
    const ushort* kt0 = kb + (size_t)(i * N) * C;
    const ushort* vt0 = vbT + (size_t)(i * H * D) * N;

    // ---- prologue: stage h=0 K/V/Q into registers
    bf8 kpre[2], vpre[2], aq;
    #pragma unroll
    for (int it = 0; it < 2; it++) {
        int idx = it * 512 + t;
        kpre[it] = *(const bf8*)(kt0 + (size_t)(idx >> 2) * C + 0 * D + (idx & 3) * 8);
        vpre[it] = *(const bf8*)(vt0 + (size_t)0 * D * N + idx * 8);
    }
    aq = *(const bf8*)(qb + (size_t)(i * N + qc * 16 + lrow) * C + 0 * D + quad * 8);

    #pragma unroll 1
    for (int h = 0; h < 4; h++) {
        barrier_lgkm();                 // prior head's Kf/Vf readers done
        // ---- write staged K/V registers into frag layouts
        #pragma unroll
        for (int it = 0; it < 2; it++) {
            int idx = it * 512 + t;
            int ck = (idx >> 6) * 64 + (idx & 3) * 16 + ((idx >> 2) & 15);
            *(bf8*)&Kf[ck * 8] = kpre[it];
            int cv = (idx >> 9) * 512 + ((idx >> 2) & 7) * 64 + (idx & 3) * 16 + ((idx >> 5) & 15);
            cv ^= (cv >> 6) & 7;
            *(bf8*)&Vf[cv * 8] = vpre[it];
        }
        bf8 aq_cur = aq;
        // ---- T14: issue next head's loads NOW; they fly under the compute
        if (h < 3) {
            #pragma unroll
            for (int it = 0; it < 2; it++) {
                int idx = it * 512 + t;
                kpre[it] = *(const bf8*)(kt0 + (size_t)(idx >> 2) * C + (h + 1) * D + (idx & 3) * 8);
                vpre[it] = *(const bf8*)(vt0 + (size_t)(h + 1) * D * N + idx * 8);
            }
            aq = *(const bf8*)(qb + (size_t)(i * N + qc * 16 + lrow) * C + (h + 1) * D + quad * 8);
        }
        barrier_lgkm();                 // staging visible block-wide

        float sum[4] = {0.f, 0.f, 0.f, 0.f};
        f32x4 o2[2];
        o2[0] = (f32x4){0.f, 0.f, 0.f, 0.f};
        o2[1] = (f32x4){0.f, 0.f, 0.f, 0.f};
        const ushort* trih = tri_p + (size_t)h * 65536;

        #pragma unroll
        for (int half = 0; half < 2; half++) {
            const ushort* tp = trih + ((size_t)(qc * 8 + half * 4) * 64 + lane) * 8;
            // ---- S = Q K^T in pairs, exp2 + P write (A-frag order)
            #pragma unroll
            for (int p = 0; p < 4; p++) {
                bf8 tf = *(const bf8*)(tp + p * 512);
                #pragma unroll
                for (int j = 0; j < 2; j++) {
                    int n8 = p * 2 + j;
                    bf8 kf = *(const bf8*)&Kf[((half * 8 + n8) * 64 + lane) * 8];
                    f32x4 s = __builtin_amdgcn_mfma_f32_16x16x32_bf16(
                        aq_cur, kf, (f32x4){0.f, 0.f, 0.f, 0.f}, 0, 0, 0);
                    int pa = (n8 >> 1) * 512 + (((n8 << 1) + l3) & 3) * 128 + pq;
                    #pragma unroll
                    for (int r = 0; r < 4; r++) {
                        float tb = bf2f(((const ushort*)&tf)[j * 4 + r]);
                        float e  = exp2f(s[r] + tb + mb[half * 8 + n8]);
                        sum[r]  += e;
                        Pw[pa + r * 8] = f2bf_trunc(e);
                    }
                }
            }
            drain_lds();               // wave-private P visible; prior reads done

            // ---- O += P V_half
            __builtin_amdgcn_s_setprio(1);
            #pragma unroll
            for (int ks = 0; ks < 4; ks++) {
                bf8 ap = *(const bf8*)&Pw[(ks * 64 + lane) * 8];
                int ksg = half * 4 + ks;
                #pragma unroll
                for (int nv = 0; nv < 2; nv++) {
                    int c = nv * 512 + ksg * 64 + (lane ^ (ksg & 7));
                    bf8 bv = *(const bf8*)&Vf[c * 8];
                    o2[nv] = __builtin_amdgcn_mfma_f32_16x16x32_bf16(ap, bv, o2[nv], 0, 0, 0);
                }
            }
            __builtin_amdgcn_s_setprio(0);
        }

        // ---- normalize + gate, transpose O to A-frag order, fused out-proj
        #pragma unroll
        for (int r = 0; r < 4; r++) {
            float s = sum[r];
            s += __shfl_xor(s, 1, 64);
            s += __shfl_xor(s, 2, 64);
            s += __shfl_xor(s, 4, 64);
            s += __shfl_xor(s, 8, 64);
            sum[r] = 1.f / s;
        }
        const ushort* gt = gate + (size_t)(i * N + qc * 16) * C + h * D;
        #pragma unroll
        for (int nv = 0; nv < 2; nv++) {
            #pragma unroll
            for (int r = 0; r < 4; r++) {
                float g = bf2f(gt[(quad * 4 + r) * C + nv * 16 + lrow]);
                float val = o2[nv][r] * sum[r] * g;
                Pw[(nv * 2 + l3) * 128 + pq + r * 8] = f2bf(val);
            }
        }
        drain_lds();

        bf8 ap2 = *(const bf8*)&Pw[lane * 8];
        __builtin_amdgcn_s_setprio(1);
        #pragma unroll
        for (int ct = 0; ct < 8; ct++) {
            bf8 wv = *(const bf8*)(Wo + (size_t)(ct * 16 + lrow) * 128 + h * D + quad * 8);
            oacc[ct] = __builtin_amdgcn_mfma_f32_16x16x32_bf16(ap2, wv, oacc[ct], 0, 0, 0);
        }
        __builtin_amdgcn_s_setprio(0);
    }

    // ---- epilogue: + bias, fp32 stores
    #pragma unroll
    for (int ct = 0; ct < 8; ct++) {
        float bias = bo[ct * 16 + lrow];
        #pragma unroll
        for (int r = 0; r < 4; r++) {
            int qg = qc * 16 + quad * 4 + r;
            out[(size_t)(i * N + qg) * C + ct * 16 + lrow] = oacc[ct][r] + bias;
        }
    }
}

// ---------------------------------------------------------------- launch
extern "C" void kernel_launch(void* const* d_in, const int* in_sizes, int n_in,
                              void* d_out, int out_size, void* d_ws, size_t ws_size,
                              hipStream_t stream)
{
    const float* x    = (const float*)d_in[0];
    const float* mask = (const float*)d_in[1];
    const float* lnw  = (const float*)d_in[2];
    const float* lnb  = (const float*)d_in[3];
    const float* wb   = (const float*)d_in[4];
    const float* wq   = (const float*)d_in[5];
    const float* wk   = (const float*)d_in[6];
    const float* wv   = (const float*)d_in[7];
    const float* wg   = (const float*)d_in[8];
    const float* bg   = (const float*)d_in[9];
    const float* wo   = (const float*)d_in[10];
    const float* bo   = (const float*)d_in[11];
    float* out = (float*)d_out;

    uintptr_t w = (uintptr_t)d_ws;
    ushort* qb    = (ushort*)w; w += (size_t)NP * C * 2;   // 16 MB
    ushort* kb    = (ushort*)w; w += (size_t)NP * C * 2;   // 16 MB
    ushort* vbT   = (ushort*)w; w += (size_t)NP * C * 2;   // 16 MB (transposed V)
    ushort* gate  = (ushort*)w; w += (size_t)NP * C * 2;   // 16 MB
    ushort* tri_p = (ushort*)w; w += (size_t)H * NP * 2;   // 0.5 MB
    ushort* Wcat  = (ushort*)w; w += 512 * 128 * 2;
    ushort* WbPad = (ushort*)w; w += 16 * 128 * 2;
    ushort* Wo    = (ushort*)w; w += 128 * 128 * 2;

    prep_weights<<<256, 256, 0, stream>>>(wq, wk, wv, wg, wb, wo, Wcat, WbPad, Wo);
    ln_proj<<<NP / 64, 256, 0, stream>>>(x, lnw, lnb, Wcat, WbPad, bg,
                                         qb, kb, vbT, gate, tri_p);
    attn_out<<<dim3(N, 2), 512, 0, stream>>>(qb, kb, vbT, tri_p, mask, gate,
                                             Wo, bo, out);
}

// Round 9
// 217.287 us; speedup vs baseline: 1.0561x; 1.0561x over previous
//
#include <hip/hip_runtime.h>

#define N 256
#define C 128
#define H 4
#define D 32
#define NP (N*N)            // 65536 pairs
#define LN_EPS 1e-5f
#define LOG2E 1.4426950408889634f

// Block-wide barrier (LDS ordering only; global stores keep flying).
__device__ __forceinline__ void barrier_lgkm() {
    __asm__ volatile("s_waitcnt lgkmcnt(0)" ::: "memory");
    __builtin_amdgcn_sched_barrier(0);
    __builtin_amdgcn_s_barrier();
    __builtin_amdgcn_sched_barrier(0);
}
// Wave-local LDS drain (no barrier).
__device__ __forceinline__ void drain_lds() {
    __asm__ volatile("s_waitcnt lgkmcnt(0)" ::: "memory");
    __builtin_amdgcn_sched_barrier(0);
}

using f32x4 = __attribute__((ext_vector_type(4))) float;
using bf8   = __attribute__((ext_vector_type(8))) short;   // 8 x bf16 (4 VGPRs)
using u16x4 = __attribute__((ext_vector_type(4))) unsigned short;

__device__ __forceinline__ float bf2f(ushort u) {
    union { uint u; float f; } v; v.u = ((uint)u) << 16; return v.f;
}
__device__ __forceinline__ ushort f2bf(float f) {           // RNE
    union { float f; uint u; } v; v.f = f;
    uint u = v.u;
    u += 0x7fffu + ((u >> 16) & 1u);
    return (ushort)(u >> 16);
}
__device__ __forceinline__ ushort f2bf_trunc(float f) {     // truncate
    union { float f; uint u; } v; v.f = f;
    return (ushort)(v.u >> 16);
}

// ---------------------------------------------------------------- weights
__global__ __launch_bounds__(256) void prep_weights(
    const float* __restrict__ wq, const float* __restrict__ wk,
    const float* __restrict__ wv, const float* __restrict__ wg,
    const float* __restrict__ wb, const float* __restrict__ wo,
    ushort* __restrict__ Wcat, ushort* __restrict__ WbPad, ushort* __restrict__ Wo)
{
    int t = blockIdx.x * 256 + threadIdx.x;    // 65536 threads
    const float scale = 0.17677669529663689f * LOG2E;
    float v;
    if (t < 16384)       v = wq[t] * scale;
    else if (t < 32768)  v = wk[t - 16384];
    else if (t < 49152)  v = wv[t - 32768];
    else                 v = wg[t - 49152];
    Wcat[t] = f2bf(v);
    if (t < 16384) Wo[t] = f2bf(wo[t]);
    if (t < 2048)  WbPad[t] = (t < 512) ? f2bf(wb[t]) : (ushort)0;
}

// ---------------------------------------------------------------- LN -> frag-order xn
// Streaming, BARRIER-FREE. 1024 blocks x 256 thr; each wave owns a 16-pair
// strip: 16 lanes/row (8 ch each, 4-step butterfly), LN result packed as one
// bf8 = one fragment chunk, staged in the wave's own LDS strip, copied out
// coalesced. xn_f layout (global, ushort):
//   F(p,c) = (p>>4)*2048 + ((c>>3)*16 + (p&15))*8 + (c&7)
// so a proj wave's A-frag load is 16B/lane fully coalesced.
__global__ __launch_bounds__(256, 8) void ln_frag(
    const float* __restrict__ x, const float* __restrict__ lnw,
    const float* __restrict__ lnb, ushort* __restrict__ xn_f)
{
    __shared__ ushort S[64 * 128];     // 16 KB: 4 wave-private strips
    int mt = blockIdx.x;               // 0..1023 (64 pairs each)
    int t  = threadIdx.x;
    int wave = t >> 6, lane = t & 63;
    int lane16 = lane & 15, rgrp = lane >> 4;

    const float4 w0 = ((const float4*)lnw)[lane16 * 2];
    const float4 w1 = ((const float4*)lnw)[lane16 * 2 + 1];
    const float4 b0 = ((const float4*)lnb)[lane16 * 2];
    const float4 b1 = ((const float4*)lnb)[lane16 * 2 + 1];
    const float* xb = x + (size_t)mt * 64 * C;

    float4 xv[4][2];
    #pragma unroll
    for (int pp = 0; pp < 4; pp++) {
        int r = wave * 16 + pp * 4 + rgrp;
        xv[pp][0] = ((const float4*)(xb + r * C))[lane16 * 2];
        xv[pp][1] = ((const float4*)(xb + r * C))[lane16 * 2 + 1];
    }
    #pragma unroll
    for (int pp = 0; pp < 4; pp++) {
        int r = wave * 16 + pp * 4 + rgrp;     // global row in block
        float4 a = xv[pp][0], b = xv[pp][1];
        float s  = a.x + a.y + a.z + a.w + b.x + b.y + b.z + b.w;
        float ss = a.x*a.x + a.y*a.y + a.z*a.z + a.w*a.w
                 + b.x*b.x + b.y*b.y + b.z*b.z + b.w*b.w;
        #pragma unroll
        for (int m = 1; m < 16; m <<= 1) {     // 16-lane butterfly
            s  += __shfl_xor(s, m, 64);
            ss += __shfl_xor(ss, m, 64);
        }
        float mean = s * (1.f / 128.f);
        float var  = ss * (1.f / 128.f) - mean * mean;
        float rstd = rsqrtf(var + LN_EPS);
        union { ushort us[8]; bf8 v8; } o;
        o.us[0] = f2bf((a.x - mean) * rstd * w0.x + b0.x);
        o.us[1] = f2bf((a.y - mean) * rstd * w0.y + b0.y);
        o.us[2] = f2bf((a.z - mean) * rstd * w0.z + b0.z);
        o.us[3] = f2bf((a.w - mean) * rstd * w0.w + b0.w);
        o.us[4] = f2bf((b.x - mean) * rstd * w1.x + b1.x);
        o.us[5] = f2bf((b.y - mean) * rstd * w1.y + b1.y);
        o.us[6] = f2bf((b.z - mean) * rstd * w1.z + b1.z);
        o.us[7] = f2bf((b.w - mean) * rstd * w1.w + b1.w);
        // chunk (row, c8=lane16), XOR-swizzled within the wave's strip
        *(bf8*)&S[wave * 2048 + ((r & 15) * 16 + (lane16 ^ (r & 7))) * 8] = o.v8;
    }
    drain_lds();                       // wave-local: own writes visible
    size_t strip = (size_t)mt * 4 + wave;
    #pragma unroll
    for (int it = 0; it < 4; it++) {
        int ci = it * 64 + lane;               // 0..255 chunks of the strip
        int c8 = ci >> 4, p15 = ci & 15;
        bf8 v = *(const bf8*)&S[wave * 2048 + (p15 * 16 + (c8 ^ (p15 & 7))) * 8];
        *(bf8*)&xn_f[strip * 2048 + (size_t)ci * 8] = v;    // 1KB/wave/iter
    }
}

// ---------------------------------------------------------------- QKVG projection + tri
// 512 blocks x 512 thr (8 waves); block covers 128 pairs (half an attn row).
// Each wave: 4 coalesced A-frag loads DIRECT from frag-order xn_f (no LDS
// staging, no entry barrier) -> tri (4 MFMAs) -> nt loop {32 B-loads from
// L2-resident Wcat, 32 MFMAs, epilogue}. q/k/gate epilogues are wave-local
// (own 4KB LDS strip + drain, no barrier); only the V transpose is
// block-cooperative (3 barriers total).
__global__ __launch_bounds__(512, 4) void proj(
    const ushort* __restrict__ xn_f, const ushort* __restrict__ Wcat,
    const ushort* __restrict__ WbPad, const float* __restrict__ bg,
    ushort* __restrict__ qb, ushort* __restrict__ kb,
    ushort* __restrict__ vbT, ushort* __restrict__ gate,
    ushort* __restrict__ tri_p)
{
    __shared__ ushort S[128 * 128];    // 32 KB: 8 wave strips / V transpose
    int mt = blockIdx.x;               // 0..511: pairs mt*128 .. +127
    int t  = threadIdx.x;
    int wave = t >> 6, lane = t & 63;
    int lrow = lane & 15, quad = lane >> 4;

    // ---- A-frags straight from global (coalesced 16B/lane)
    const ushort* af = xn_f + ((size_t)mt * 8 + wave) * 2048;
    bf8 afr[4];
    #pragma unroll
    for (int ks = 0; ks < 4; ks++)
        afr[ks] = *(const bf8*)(af + ((ks * 4 + quad) * 16 + lrow) * 8);

    // ---- triangle bias for this wave's 16 pairs
    {
        f32x4 at = (f32x4){0.f, 0.f, 0.f, 0.f};
        #pragma unroll
        for (int ks = 0; ks < 4; ks++) {
            bf8 bt = *(const bf8*)(WbPad + lrow * C + (ks * 4 + quad) * 8);
            at = __builtin_amdgcn_mfma_f32_16x16x32_bf16(afr[ks], bt, at, 0, 0, 0);
        }
        if (lrow < 4) {                // lrow = h
            int q = mt >> 1;
            int qc = q >> 4, quadq = (q >> 2) & 3, rr = q & 3;
            #pragma unroll
            for (int r = 0; r < 4; r++) {
                int k = (mt & 1) * 128 + wave * 16 + quad * 4 + r;
                int n = k >> 4, lk = k & 15;
                int lanet = quadq * 16 + lk;
                int v2 = n * 4 + rr, j = v2 >> 3, m2 = v2 & 7;
                tri_p[lrow * 65536 + ((qc * 8 + j) * 64 + lanet) * 8 + m2] =
                    f2bf(at[r] * LOG2E);
            }
        }
    }

    ushort* Sw = S + wave * 2048;      // wave-private [16][128] strip
    #pragma unroll 1
    for (int nt = 0; nt < 4; nt++) {
        const ushort* Wt = Wcat + (size_t)nt * 128 * C;
        f32x4 acc[8];
        #pragma unroll
        for (int ni = 0; ni < 8; ni++) acc[ni] = (f32x4){0.f, 0.f, 0.f, 0.f};
        #pragma unroll
        for (int ks = 0; ks < 4; ks++) {
            #pragma unroll
            for (int ni = 0; ni < 8; ni++) {
                bf8 b = *(const bf8*)(Wt + (size_t)(ni * 16 + lrow) * C + (ks * 4 + quad) * 8);
                acc[ni] = __builtin_amdgcn_mfma_f32_16x16x32_bf16(afr[ks], b, acc[ni], 0, 0, 0);
            }
        }

        if (nt == 2) {
            barrier_lgkm();            // all strips free (waves drained own LDS)
            // stage V col-major [col 128][key 128], swizzled
            #pragma unroll
            for (int ni = 0; ni < 8; ni++) {
                int col = ni * 16 + lrow;
                #pragma unroll
                for (int r = 0; r < 4; r++) {
                    int key = wave * 16 + quad * 4 + r;      // local 0..127
                    S[col * 128 + (key ^ ((col & 7) << 3))] = f2bf(acc[ni][r]);
                }
            }
            barrier_lgkm();
            int i_row = mt >> 1, keybase = (mt & 1) * 128;
            #pragma unroll
            for (int it = 0; it < 4; it++) {
                int cidx = it * 512 + t;           // 0..2047
                int col = cidx >> 4, kc = cidx & 15;
                bf8 v = *(const bf8*)&S[col * 128 + ((kc * 8) ^ ((col & 7) << 3))];
                *(bf8*)&vbT[(size_t)(i_row * 128 + col) * N + keybase + kc * 8] = v;
            }
            barrier_lgkm();            // strips reusable for nt=3
        } else {
            ushort* dst = (nt == 0) ? qb : (nt == 1) ? kb : gate;
            #pragma unroll
            for (int ni = 0; ni < 8; ni++) {
                int col = ni * 16 + lrow;
                float gb = (nt == 3) ? bg[col] : 0.f;
                int colS = col ^ (quad << 3);
                #pragma unroll
                for (int r = 0; r < 4; r++) {
                    float vv = acc[ni][r];
                    if (nt == 3) vv = 1.f / (1.f + __expf(-(vv + gb)));
                    Sw[(quad * 4 + r) * 128 + colS] = f2bf(vv);
                }
            }
            drain_lds();               // wave-local
            #pragma unroll
            for (int it = 0; it < 4; it++) {
                int ci = it * 64 + lane;           // 0..255
                int row = ci >> 4, c8 = ci & 15;
                bf8 v = *(const bf8*)&Sw[row * 128 + (c8 ^ ((row >> 2) & 3)) * 8];
                *(bf8*)&dst[(size_t)(mt * 128 + wave * 16 + row) * C + c8 * 8] = v;
            }
        }
    }
}

// ---------------------------------------------------------------- fused attention + out-proj
// (R6 form -- best measured variant.) Grid (i=256, qh=2), 512 thr = 8 waves.
__global__ __launch_bounds__(512, 4) void attn_out(
    const ushort* __restrict__ qb, const ushort* __restrict__ kb,
    const ushort* __restrict__ vbT, const ushort* __restrict__ tri_p,
    const float* __restrict__ mask, const ushort* __restrict__ gate,
    const ushort* __restrict__ Wo, const float* __restrict__ bo,
    float* __restrict__ out)
{
    __shared__ ushort Kf[8192];       // 16 KB, per-head K fragments
    __shared__ ushort Vf[8192];       // 16 KB, per-head V fragments (swizzled)
    __shared__ ushort Pf[8][2048];    // 32 KB: per-wave P / O-transpose buffer

    int i  = blockIdx.x;
    int qh = blockIdx.y;
    int t  = threadIdx.x;
    int wave = t >> 6, lane = t & 63;
    int lrow = lane & 15, quad = lane >> 4;
    int qc = qh * 8 + wave;            // q-chunk 0..15

    float mb[16];
    #pragma unroll
    for (int n = 0; n < 16; n++)
        mb[n] = (1e9f * LOG2E) * (mask[i * N + n * 16 + lrow] - 1.0f);

    f32x4 oacc[8];
    #pragma unroll
    for (int ct = 0; ct < 8; ct++) oacc[ct] = (f32x4){0.f, 0.f, 0.f, 0.f};

    ushort* Pw = &Pf[wave][0];
    const int pq = quad * 32 + (lrow & 7);
    const int l3 = (lrow >> 3) & 1;

    #pragma unroll 1
    for (int h = 0; h < 4; h++) {
        bf8 aq = *(const bf8*)(qb + (size_t)(i * N + qc * 16 + lrow) * C
                               + h * D + quad * 8);
        barrier_lgkm();                 // prior head's Kf/Vf readers done
        {
            const ushort* kt = kb + (size_t)(i * N) * C + h * D;
            #pragma unroll
            for (int it = 0; it < 2; it++) {
                int idx = it * 512 + t;
                int key = idx >> 2, d0 = (idx & 3) * 8;
                bf8 kv = *(const bf8*)(kt + (size_t)key * C + d0);
                int c = (idx >> 6) * 64 + (idx & 3) * 16 + ((idx >> 2) & 15);
                *(bf8*)&Kf[c * 8] = kv;
            }
        }
        {
            const ushort* vt = vbT + (size_t)((i * H + h) * D) * N;
            #pragma unroll
            for (int it = 0; it < 2; it++) {
                int idx = it * 512 + t;
                bf8 vv = *(const bf8*)(vt + idx * 8);
                int c = (idx >> 9) * 512 + ((idx >> 2) & 7) * 64 + (idx & 3) * 16 + ((idx >> 5) & 15);
                c ^= (c >> 6) & 7;
                *(bf8*)&Vf[c * 8] = vv;
            }
        }
        barrier_lgkm();

        float sum[4] = {0.f, 0.f, 0.f, 0.f};
        f32x4 o2[2];
        o2[0] = (f32x4){0.f, 0.f, 0.f, 0.f};
        o2[1] = (f32x4){0.f, 0.f, 0.f, 0.f};
        const ushort* trih = tri_p + (size_t)h * 65536;

        #pragma unroll
        for (int half = 0; half < 2; half++) {
            const ushort* tp = trih + ((size_t)(qc * 8 + half * 4) * 64 + lane) * 8;
            #pragma unroll
            for (int p = 0; p < 4; p++) {
                bf8 tf = *(const bf8*)(tp + p * 512);
                #pragma unroll
                for (int j = 0; j < 2; j++) {
                    int n8 = p * 2 + j;
                    bf8 kf = *(const bf8*)&Kf[((half * 8 + n8) * 64 + lane) * 8];
                    f32x4 s = __builtin_amdgcn_mfma_f32_16x16x32_bf16(
                        aq, kf, (f32x4){0.f, 0.f, 0.f, 0.f}, 0, 0, 0);
                    int pa = (n8 >> 1) * 512 + (((n8 << 1) + l3) & 3) * 128 + pq;
                    #pragma unroll
                    for (int r = 0; r < 4; r++) {
                        float tb = bf2f(((const ushort*)&tf)[j * 4 + r]);
                        float e  = exp2f(s[r] + tb + mb[half * 8 + n8]);
                        sum[r]  += e;
                        Pw[pa + r * 8] = f2bf_trunc(e);
                    }
                }
            }
            drain_lds();

            __builtin_amdgcn_s_setprio(1);
            #pragma unroll
            for (int ks = 0; ks < 4; ks++) {
                bf8 ap = *(const bf8*)&Pw[(ks * 64 + lane) * 8];
                int ksg = half * 4 + ks;
                #pragma unroll
                for (int nv = 0; nv < 2; nv++) {
                    int c = nv * 512 + ksg * 64 + (lane ^ (ksg & 7));
                    bf8 bv = *(const bf8*)&Vf[c * 8];
                    o2[nv] = __builtin_amdgcn_mfma_f32_16x16x32_bf16(ap, bv, o2[nv], 0, 0, 0);
                }
            }
            __builtin_amdgcn_s_setprio(0);
        }

        #pragma unroll
        for (int r = 0; r < 4; r++) {
            float s = sum[r];
            s += __shfl_xor(s, 1, 64);
            s += __shfl_xor(s, 2, 64);
            s += __shfl_xor(s, 4, 64);
            s += __shfl_xor(s, 8, 64);
            sum[r] = 1.f / s;
        }
        const ushort* gt = gate + (size_t)(i * N + qc * 16) * C + h * D;
        #pragma unroll
        for (int nv = 0; nv < 2; nv++) {
            #pragma unroll
            for (int r = 0; r < 4; r++) {
                float g = bf2f(gt[(quad * 4 + r) * C + nv * 16 + lrow]);
                float val = o2[nv][r] * sum[r] * g;
                Pw[(nv * 2 + l3) * 128 + pq + r * 8] = f2bf(val);
            }
        }
        drain_lds();

        bf8 ap2 = *(const bf8*)&Pw[lane * 8];
        __builtin_amdgcn_s_setprio(1);
        #pragma unroll
        for (int ct = 0; ct < 8; ct++) {
            bf8 wv = *(const bf8*)(Wo + (size_t)(ct * 16 + lrow) * 128 + h * D + quad * 8);
            oacc[ct] = __builtin_amdgcn_mfma_f32_16x16x32_bf16(ap2, wv, oacc[ct], 0, 0, 0);
        }
        __builtin_amdgcn_s_setprio(0);
    }

    #pragma unroll
    for (int ct = 0; ct < 8; ct++) {
        float bias = bo[ct * 16 + lrow];
        #pragma unroll
        for (int r = 0; r < 4; r++) {
            int qg = qc * 16 + quad * 4 + r;
            out[(size_t)(i * N + qg) * C + ct * 16 + lrow] = oacc[ct][r] + bias;
        }
    }
}

// ---------------------------------------------------------------- launch
extern "C" void kernel_launch(void* const* d_in, const int* in_sizes, int n_in,
                              void* d_out, int out_size, void* d_ws, size_t ws_size,
                              hipStream_t stream)
{
    const float* x    = (const float*)d_in[0];
    const float* mask = (const float*)d_in[1];
    const float* lnw  = (const float*)d_in[2];
    const float* lnb  = (const float*)d_in[3];
    const float* wb   = (const float*)d_in[4];
    const float* wq   = (const float*)d_in[5];
    const float* wk   = (const float*)d_in[6];
    const float* wv   = (const float*)d_in[7];
    const float* wg   = (const float*)d_in[8];
    const float* bg   = (const float*)d_in[9];
    const float* wo   = (const float*)d_in[10];
    const float* bo   = (const float*)d_in[11];
    float* out = (float*)d_out;

    uintptr_t w = (uintptr_t)d_ws;
    ushort* xn_f  = (ushort*)w; w += (size_t)NP * C * 2;   // 16 MB (frag-order LN)
    ushort* qb    = (ushort*)w; w += (size_t)NP * C * 2;   // 16 MB
    ushort* kb    = (ushort*)w; w += (size_t)NP * C * 2;   // 16 MB
    ushort* vbT   = (ushort*)w; w += (size_t)NP * C * 2;   // 16 MB (transposed V)
    ushort* gate  = (ushort*)w; w += (size_t)NP * C * 2;   // 16 MB
    ushort* tri_p = (ushort*)w; w += (size_t)H * NP * 2;   // 0.5 MB
    ushort* Wcat  = (ushort*)w; w += 512 * 128 * 2;
    ushort* WbPad = (ushort*)w; w += 16 * 128 * 2;
    ushort* Wo    = (ushort*)w; w += 128 * 128 * 2;

    prep_weights<<<256, 256, 0, stream>>>(wq, wk, wv, wg, wb, wo, Wcat, WbPad, Wo);
    ln_frag<<<NP / 64, 256, 0, stream>>>(x, lnw, lnb, xn_f);
    proj<<<NP / 128, 512, 0, stream>>>(xn_f, Wcat, WbPad, bg,
                                       qb, kb, vbT, gate, tri_p);
    attn_out<<<dim3(N, 2), 512, 0, stream>>>(qb, kb, vbT, tri_p, mask, gate,
                                             Wo, bo, out);
}